// Round 4
// baseline (81.518 us; speedup 1.0000x reference)
//
#include <hip/hip_runtime.h>
#include <hip/hip_bf16.h>

typedef __attribute__((ext_vector_type(4))) float f32x4;
typedef __attribute__((ext_vector_type(8))) short short8;
typedef __attribute__((ext_vector_type(4))) unsigned short ushort4v;
typedef _Float16 f16x8 __attribute__((ext_vector_type(8)));

#define NB 8
#define NN 2048
#define NF 128
#define LOG2E 1.4426950408889634f
#define MASK_NEG_H -60000.0f

static __device__ __forceinline__ unsigned short f2bf(float f) {
    union { __hip_bfloat16 b; unsigned short u; } cv;
    cv.b = __float2bfloat16(f);
    return cv.u;
}

// ---------------------------------------------------------------------------
// Kernel A: h_prime = h @ W via bf16 MFMA -> hpT (bf16, [b][f][n]);
// siC/sjC = (h @ (W@a1,2)) * log2e in fp32 (exact GEMV, fused).
// ---------------------------------------------------------------------------
__global__ __launch_bounds__(256) void k_hprime(
    const float* __restrict__ h, const float* __restrict__ W,
    const float* __restrict__ a, unsigned short* __restrict__ hpT,
    float* __restrict__ siC, float* __restrict__ sjC)
{
    __shared__ __align__(16) unsigned char WT[32768];  // W^T bf16, swizzled [col][f]
    __shared__ float wa1[NF], wa2[NF];

    const int t = threadIdx.x;
    const int lane = t & 63;
    const int w = t >> 6;                 // 4 waves
    const int b = blockIdx.x >> 5;
    const int i0 = (blockIdx.x & 31) << 6;

    {
        const int f = t >> 1;             // 0..127
        const int c0 = (t & 1) << 6;      // 0 or 64
        float s1 = 0.f, s2 = 0.f;
        const float* wrow = W + f * NF + c0;
        const float* a1p = a + c0;
        const float* a2p = a + NF + c0;
        #pragma unroll 8
        for (int c = 0; c < 64; ++c) {
            float wv = wrow[c];
            s1 += wv * a1p[c];
            s2 += wv * a2p[c];
            int col = c0 + c;
            int dst = col * 256 + ((2 * f) ^ ((col & 15) << 4));
            *reinterpret_cast<unsigned short*>(&WT[dst]) = f2bf(wv);
        }
        s1 += __shfl_xor(s1, 1);
        s2 += __shfl_xor(s2, 1);
        if ((t & 1) == 0) { wa1[f] = s1 * LOG2E; wa2[f] = s2 * LOG2E; }
    }
    __syncthreads();

    const int arow = i0 + w * 16 + (lane & 15);
    const int kofs = (lane >> 4) << 3;    // 0,8,16,24
    const float* hrow = h + (size_t)(b * NN + arow) * NF + kofs;
    const int swz = (lane & 15) << 4;

    f32x4 acc[8];
    #pragma unroll
    for (int nt = 0; nt < 8; ++nt) acc[nt] = (f32x4)(0.f);
    float s1 = 0.f, s2 = 0.f;

    #pragma unroll
    for (int k0 = 0; k0 < NF; k0 += 32) {
        f32x4 h0 = *reinterpret_cast<const f32x4*>(hrow + k0);
        f32x4 h1 = *reinterpret_cast<const f32x4*>(hrow + k0 + 4);
        f32x4 w1lo = *reinterpret_cast<const f32x4*>(&wa1[k0 + kofs]);
        f32x4 w1hi = *reinterpret_cast<const f32x4*>(&wa1[k0 + kofs + 4]);
        f32x4 w2lo = *reinterpret_cast<const f32x4*>(&wa2[k0 + kofs]);
        f32x4 w2hi = *reinterpret_cast<const f32x4*>(&wa2[k0 + kofs + 4]);
        short8 af;
        #pragma unroll
        for (int e = 0; e < 4; ++e) {
            s1 += h0[e] * w1lo[e] + h1[e] * w1hi[e];
            s2 += h0[e] * w2lo[e] + h1[e] * w2hi[e];
            af[e]     = (short)f2bf(h0[e]);
            af[4 + e] = (short)f2bf(h1[e]);
        }
        const int ib = (2 * (k0 + kofs)) ^ swz;
        #pragma unroll
        for (int nt = 0; nt < 8; ++nt) {
            short8 bf8 = *reinterpret_cast<short8*>(&WT[(nt * 16 + (lane & 15)) * 256 + ib]);
            acc[nt] = __builtin_amdgcn_mfma_f32_16x16x32_bf16(af, bf8, acc[nt], 0, 0, 0);
        }
    }

    s1 += __shfl_xor(s1, 16); s1 += __shfl_xor(s1, 32);
    s2 += __shfl_xor(s2, 16); s2 += __shfl_xor(s2, 32);
    if (lane < 16) {
        siC[b * NN + arow] = s1;
        sjC[b * NN + arow] = s2;
    }

    #pragma unroll
    for (int nt = 0; nt < 8; ++nt) {
        int col = nt * 16 + (lane & 15);
        ushort4v pk;
        #pragma unroll
        for (int e = 0; e < 4; ++e) pk[e] = f2bf(acc[nt][e]);
        *reinterpret_cast<ushort4v*>(
            hpT + (size_t)(b * NF + col) * NN + i0 + w * 16 + ((lane >> 4) << 2)) = pk;
    }
}

// ---------------------------------------------------------------------------
// Kernel B: biasH[i][j] = fp16( adj>0 ? -log2(dist+1e-6)*scale : -60000 )
// ---------------------------------------------------------------------------
__global__ __launch_bounds__(256) void k_bias(
    const int* __restrict__ adj, const float* __restrict__ dist,
    const float* __restrict__ scaler, _Float16* __restrict__ biasH)
{
    const int idx = (blockIdx.x * 256 + threadIdx.x) * 8;
    const float sc = scaler[0];
    int4 a0 = *reinterpret_cast<const int4*>(adj + idx);
    int4 a1 = *reinterpret_cast<const int4*>(adj + idx + 4);
    float4 d0 = *reinterpret_cast<const float4*>(dist + idx);
    float4 d1 = *reinterpret_cast<const float4*>(dist + idx + 4);
    f16x8 ov;
    ov[0] = (_Float16)((a0.x > 0) ? (-__log2f(d0.x + 1e-6f) * sc) : MASK_NEG_H);
    ov[1] = (_Float16)((a0.y > 0) ? (-__log2f(d0.y + 1e-6f) * sc) : MASK_NEG_H);
    ov[2] = (_Float16)((a0.z > 0) ? (-__log2f(d0.z + 1e-6f) * sc) : MASK_NEG_H);
    ov[3] = (_Float16)((a0.w > 0) ? (-__log2f(d0.w + 1e-6f) * sc) : MASK_NEG_H);
    ov[4] = (_Float16)((a1.x > 0) ? (-__log2f(d1.x + 1e-6f) * sc) : MASK_NEG_H);
    ov[5] = (_Float16)((a1.y > 0) ? (-__log2f(d1.y + 1e-6f) * sc) : MASK_NEG_H);
    ov[6] = (_Float16)((a1.z > 0) ? (-__log2f(d1.z + 1e-6f) * sc) : MASK_NEG_H);
    ov[7] = (_Float16)((a1.w > 0) ? (-__log2f(d1.w + 1e-6f) * sc) : MASK_NEG_H);
    *reinterpret_cast<f16x8*>(biasH + idx) = ov;
}

// ---------------------------------------------------------------------------
// Kernel C: barrier-free flash GAT. Block = 8 waves, 32 i-rows; wave w owns
// j-strip [w*256, w*256+256) over ALL 128 cols (rs=2 rowsets x nt=8).
// B-frags read straight from L2 (V[b] = 512KB, pinned hot via XCD=batch
// swizzle). Zero main-loop barriers; 6-barrier LDS tree combine at end.
// ---------------------------------------------------------------------------
__global__ __launch_bounds__(512, 4) void k_attn(
    const unsigned short* __restrict__ hpT, const float* __restrict__ siC,
    const float* __restrict__ sjC, const _Float16* __restrict__ biasH,
    float* __restrict__ out)
{
    __shared__ __align__(16) unsigned char sm[50176];  // 3x16KB regions + 1KB lsum

    const int t = threadIdx.x;
    const int lane = t & 63;
    const int w = t >> 6;          // = jh, 0..7
    const int l15 = lane & 15;
    const int hi = lane >> 4;      // 0..3

    // XCD x = batch x; rg = row-group of 32
    const int b = blockIdx.x & 7;
    const int rg = blockIdx.x >> 3;

    const int irow0 = rg * 32 + l15;
    const int irow1 = irow0 + 16;
    const float si0 = siC[b * NN + irow0];
    const float si1 = siC[b * NN + irow1];

    const int jbase = w * 256 + hi * 8;
    const _Float16* bp0 = biasH + (size_t)irow0 * NN + jbase;
    const _Float16* bp1 = biasH + (size_t)irow1 * NN + jbase;
    const float* sjp = sjC + b * NN + jbase;
    const unsigned short* vp = hpT + (size_t)(b * NF + l15) * NN + jbase;

    f32x4 acc[2][8];
    #pragma unroll
    for (int rs = 0; rs < 2; ++rs)
        #pragma unroll
        for (int nt = 0; nt < 8; ++nt) acc[rs][nt] = (f32x4)(0.f);
    float ls0 = 0.f, ls1 = 0.f;

    #pragma unroll 2
    for (int step = 0; step < 8; ++step) {
        const int jo = step * 32;
        f16x8 bv0 = *reinterpret_cast<const f16x8*>(bp0 + jo);
        f16x8 bv1 = *reinterpret_cast<const f16x8*>(bp1 + jo);
        f32x4 sj0 = *reinterpret_cast<const f32x4*>(sjp + jo);
        f32x4 sj1 = *reinterpret_cast<const f32x4*>(sjp + jo + 4);
        short8 pa0, pa1;
        #pragma unroll
        for (int e = 0; e < 8; ++e) {
            const float sjv = (e < 4) ? sj0[e] : sj1[e - 4];
            float x0 = si0 + sjv;
            x0 = fmaxf(x0, 0.2f * x0) + (float)bv0[e];
            float p0 = __builtin_amdgcn_exp2f(x0);
            ls0 += p0;
            pa0[e] = (short)f2bf(p0);
            float x1 = si1 + sjv;
            x1 = fmaxf(x1, 0.2f * x1) + (float)bv1[e];
            float p1 = __builtin_amdgcn_exp2f(x1);
            ls1 += p1;
            pa1[e] = (short)f2bf(p1);
        }
        #pragma unroll
        for (int nt = 0; nt < 8; ++nt) {
            const short8 bfr = *reinterpret_cast<const short8*>(vp + nt * 16 * NN + jo);
            acc[0][nt] = __builtin_amdgcn_mfma_f32_16x16x32_bf16(pa0, bfr, acc[0][nt], 0, 0, 0);
            acc[1][nt] = __builtin_amdgcn_mfma_f32_16x16x32_bf16(pa1, bfr, acc[1][nt], 0, 0, 0);
        }
    }

    // per-row strip sums -> lanes with same l15
    ls0 += __shfl_xor(ls0, 16); ls0 += __shfl_xor(ls0, 32);
    ls1 += __shfl_xor(ls1, 16); ls1 += __shfl_xor(ls1, 32);

    float* lp = (float*)(sm + 49152);        // [8][2][16]
    if (lane < 16) { lp[w * 32 + l15] = ls0; lp[w * 32 + 16 + l15] = ls1; }

    // ---- 6-barrier tree combine of the 8 j-strip partials ----
    #define WREG(r) { f32x4* base = (f32x4*)(sm + (r) * 16384);               \
        _Pragma("unroll") for (int rs = 0; rs < 2; ++rs)                      \
        _Pragma("unroll") for (int nt = 0; nt < 8; ++nt)                      \
            base[(rs * 8 + nt) * 64 + lane] = acc[rs][nt]; }
    #define AREG(r) { f32x4* base = (f32x4*)(sm + (r) * 16384);               \
        _Pragma("unroll") for (int rs = 0; rs < 2; ++rs)                      \
        _Pragma("unroll") for (int nt = 0; nt < 8; ++nt)                      \
            acc[rs][nt] += base[(rs * 8 + nt) * 64 + lane]; }

    if (w == 4) WREG(0) else if (w == 5) WREG(1) else if (w == 6) WREG(2)
    __syncthreads();
    if (w == 0) AREG(0) else if (w == 1) AREG(1) else if (w == 2) AREG(2)
    __syncthreads();
    if (w == 7) WREG(0) else if (w == 3) WREG(1)
    __syncthreads();
    if (w == 0) AREG(0) else if (w == 1) AREG(1)
    __syncthreads();
    if (w == 1) WREG(0) else if (w == 2) WREG(1)
    __syncthreads();

    if (w == 0) {
        AREG(0) AREG(1)
        float tl0 = 0.f, tl1 = 0.f;
        #pragma unroll
        for (int q = 0; q < 8; ++q) {
            tl0 += lp[q * 32 + l15];
            tl1 += lp[q * 32 + 16 + l15];
        }
        float linv0[4], linv1[4];
        #pragma unroll
        for (int e = 0; e < 4; ++e) {
            linv0[e] = 1.0f / __shfl(tl0, hi * 4 + e);
            linv1[e] = 1.0f / __shfl(tl1, hi * 4 + e);
        }
        #pragma unroll
        for (int nt = 0; nt < 8; ++nt) {
            #pragma unroll
            for (int e = 0; e < 4; ++e) {
                const int col = nt * 16 + l15;
                float v0 = acc[0][nt][e] * linv0[e];
                v0 = (v0 > 0.f) ? v0 : expm1f(v0);
                out[(size_t)(b * NN + rg * 32 + hi * 4 + e) * NF + col] = v0;
                float v1 = acc[1][nt][e] * linv1[e];
                v1 = (v1 > 0.f) ? v1 : expm1f(v1);
                out[(size_t)(b * NN + rg * 32 + 16 + hi * 4 + e) * NF + col] = v1;
            }
        }
    }
    #undef WREG
    #undef AREG
}

extern "C" void kernel_launch(void* const* d_in, const int* in_sizes, int n_in,
                              void* d_out, int out_size, void* d_ws, size_t ws_size,
                              hipStream_t stream) {
    (void)in_sizes; (void)n_in; (void)out_size; (void)ws_size;
    const float* h      = (const float*)d_in[0];
    const int*   adj    = (const int*)d_in[1];
    const float* dist   = (const float*)d_in[2];
    const float* W      = (const float*)d_in[3];
    const float* a      = (const float*)d_in[4];
    const float* scaler = (const float*)d_in[5];
    float* out = (float*)d_out;

    char* ws = (char*)d_ws;
    unsigned short* hpT = (unsigned short*)ws;                   // 4 MiB
    float* siC     = (float*)(ws + 4 * 1024 * 1024);             // 8 KiB used
    float* sjC     = (float*)(ws + 4 * 1024 * 1024 + 65536);     // 8 KiB used
    _Float16* biasH = (_Float16*)(ws + 4 * 1024 * 1024 + 2 * 65536); // 8 MiB

    k_hprime<<<dim3(NB * NN / 64), dim3(256), 0, stream>>>(h, W, a, hpT, siC, sjC);
    k_bias<<<dim3(NN * NN / 2048), dim3(256), 0, stream>>>(adj, dist, scaler, biasH);
    k_attn<<<dim3(NB * NN / 32), dim3(512), 0, stream>>>(hpT, siC, sjC, biasH, out);
}